// Round 13
// baseline (206.794 us; speedup 1.0000x reference)
//
#include <hip/hip_runtime.h>

// MPNN (NNConv x2 + final linear) on MI355X — sorted-stream edge GEMM with
// wave-private LDS ring for B (global_load_lds, 6-deep, counted vmcnt).
// msg[p] = Z @ B at dst-sorted position p; Z[p, i*64+k] = x[esrc[p],i]*eas[p,k].
// 1-wave blocks (64 edges x 32 cols, blockIdx.y = col half): no barriers;
// 20KB of B in flight per wave -> L2-BW-bound, not latency-bound.
// Reduce: contiguous segment sum + fused root linear (+ final linear on L1).

#define NNODES 10000
#define NEDGES 50000
#define CH 64
#define NSTAGES 65     // 64 i-stages + 1 bias stage
#define MW 64          // edges per wave

typedef _Float16 f16;
typedef f16 f16x8 __attribute__((ext_vector_type(8)));
typedef float f32x4 __attribute__((ext_vector_type(4)));

#define GLOAD_LDS16(gptr, lptr) __builtin_amdgcn_global_load_lds(               \
        (const __attribute__((address_space(1))) void*)(gptr),                  \
        (__attribute__((address_space(3))) void*)(lptr), 16, 0, 0)

// ---------------- sorting (dst-order CSR) ----------------

__global__ void hist_kernel(const int* __restrict__ ei, int* __restrict__ hist) {
    int e = blockIdx.x * 256 + threadIdx.x;
    if (e < NEDGES) atomicAdd(&hist[ei[NEDGES + e]], 1);
}

__global__ __launch_bounds__(1024)
void scan_kernel(const int* __restrict__ hist, int* __restrict__ start) {
    __shared__ int buf[1024];
    int t = threadIdx.x;
    int base = t * 10;
    int loc[10];
    int s = 0;
#pragma unroll
    for (int i = 0; i < 10; ++i) {
        int n = base + i;
        int v = (n < NNODES) ? hist[n] : 0;
        loc[i] = s; s += v;
    }
    buf[t] = s;
    __syncthreads();
    for (int off = 1; off < 1024; off <<= 1) {
        int add = (t >= off) ? buf[t - off] : 0;
        __syncthreads();
        buf[t] += add;
        __syncthreads();
    }
    int ebase = buf[t] - s;
#pragma unroll
    for (int i = 0; i < 10; ++i) {
        int n = base + i;
        if (n < NNODES) start[n] = ebase + loc[i];
    }
    if (t == 1023) start[NNODES] = buf[1023];
}

__global__ void perm_kernel(const int* __restrict__ ei,
                            const int* __restrict__ start,
                            int* __restrict__ cursor,
                            int* __restrict__ eperm,
                            int* __restrict__ esrc) {
    int e = blockIdx.x * 256 + threadIdx.x;
    if (e < NEDGES) {
        int d = ei[NEDGES + e];
        int pos = start[d] + atomicAdd(&cursor[d], 1);
        eperm[pos] = e;
        esrc[pos]  = ei[e];
    }
}

// eas[p][c] = ea[eperm[p]][c]  (sorted ea rows)
__global__ void eagather_kernel(const float* __restrict__ ea,
                                const int* __restrict__ eperm,
                                float* __restrict__ eas) {
    int idx = blockIdx.x * 256 + threadIdx.x;
    if (idx >= NEDGES * 16) return;
    int p = idx >> 4, quad = idx & 15;
    int e = eperm[p];
    *(float4*)(eas + (size_t)p * 64 + quad * 4) =
        *(const float4*)(ea + (size_t)e * 64 + quad * 4);
}

// ---------------- B packing (fragment-major, both layers) ----------------
// frag id f = (s*8 + q2)*64 + ln  (q2 = tn*2+h), 16B each:
//   col = tn*16 + (ln&15), koff = h*32 + (ln>>4)*8 + j, j=0..7
//   s<64:  nn_w[koff*4096 + s*64 + col] ; s==64: nn_b[koff*64 + col]
__global__ void pack_b_kernel(const float* __restrict__ nw0, const float* __restrict__ nb0,
                              const float* __restrict__ nw1, const float* __restrict__ nb1,
                              f16* __restrict__ Bp0, f16* __restrict__ Bp1) {
    int idx = blockIdx.x * 256 + threadIdx.x;
    if (idx >= 2 * NSTAGES * 2048) return;
    int layer = (idx >= NSTAGES * 2048) ? 1 : 0;
    int r = idx - layer * NSTAGES * 2048;
    const float* nn_w = layer ? nw1 : nw0;
    const float* nn_b = layer ? nb1 : nb0;
    f16* Bp = layer ? Bp1 : Bp0;
    int p  = r & 3;
    int f  = r >> 2;
    int ln = f & 63;
    int q2 = (f >> 6) & 7;
    int s  = f >> 9;
    int tn = q2 >> 1, h = q2 & 1;
    int col  = tn * 16 + (ln & 15);
    int koff = h * 32 + (ln >> 4) * 8 + p * 2;
    float v0, v1;
    if (s < 64) {
        v0 = nn_w[(size_t)koff * 4096 + s * 64 + col];
        v1 = nn_w[(size_t)(koff + 1) * 4096 + s * 64 + col];
    } else {
        v0 = nn_b[koff * 64 + col];
        v1 = nn_b[(koff + 1) * 64 + col];
    }
    union { f16 h2[2]; unsigned u; } pk;
    pk.h2[0] = (f16)v0; pk.h2[1] = (f16)v1;
    *(unsigned*)((char*)Bp + (size_t)f * 16 + p * 4) = pk.u;
}

// ------- edge GEMM: 1 wave, 64 sorted edges x 32 cols (by = col half) -------
template<bool RELU_IN>
__global__ __launch_bounds__(64)
void edge_gemm_kernel(const float* __restrict__ x,
                      const int* __restrict__ esrc,   // sorted src ids
                      const float* __restrict__ eas,  // sorted ea rows
                      const f16* __restrict__ Bp,     // fragment-major
                      float* __restrict__ msg) {      // [E][64] at sorted pos
    __shared__ f16 xjS[MW][72];                       //  9,216 B
    __shared__ __align__(16) f16 BS[6][2048];         // 24,576 B ring

    int ln  = threadIdx.x;
    int l15 = ln & 15, l4 = ln >> 4;
    int e0  = blockIdx.x * MW;
    int nh  = blockIdx.y;          // col half 0/1

    // Gather x[src] rows (fused ReLU) into LDS as f16: 64 edges x 16 float4.
#pragma unroll
    for (int r = 0; r < 16; ++r) {
        int idx = r * 64 + ln;
        int el = idx >> 4, ip = idx & 15;
        int p  = e0 + el;
        float4 v = {0.f, 0.f, 0.f, 0.f};
        if (p < NEDGES)
            v = *(const float4*)(x + (size_t)esrc[p] * CH + ip * 4);
        if (RELU_IN) {
            v.x = fmaxf(v.x, 0.f); v.y = fmaxf(v.y, 0.f);
            v.z = fmaxf(v.z, 0.f); v.w = fmaxf(v.w, 0.f);
        }
        union { f16 h4[4]; uint2 u; } pk;
        pk.h4[0] = (f16)v.x; pk.h4[1] = (f16)v.y;
        pk.h4[2] = (f16)v.z; pk.h4[3] = (f16)v.w;
        *(uint2*)&xjS[el][ip * 4] = pk.u;
    }

    // ea fragments (stage-invariant): 4 m-tiles x 2 halves, contiguous rows
    f16x8 eav[4][2];
#pragma unroll
    for (int ms = 0; ms < 4; ++ms) {
        int p = e0 + ms * 16 + l15;
#pragma unroll
        for (int h = 0; h < 2; ++h) {
            float4 a = {0.f,0.f,0.f,0.f}, b = {0.f,0.f,0.f,0.f};
            if (p < NEDGES) {
                const float4* q = (const float4*)(eas + (size_t)p * CH + h * 32 + l4 * 8);
                a = q[0]; b = q[1];
            }
            f16x8 f;
            f[0]=(f16)a.x; f[1]=(f16)a.y; f[2]=(f16)a.z; f[3]=(f16)a.w;
            f[4]=(f16)b.x; f[5]=(f16)b.y; f[6]=(f16)b.z; f[7]=(f16)b.w;
            eav[ms][h] = f;
        }
    }

    f32x4 acc[4][2];
#pragma unroll
    for (int ms = 0; ms < 4; ++ms)
#pragma unroll
        for (int tl = 0; tl < 2; ++tl)
            acc[ms][tl] = (f32x4){0.f, 0.f, 0.f, 0.f};

    // B stage s (col half nh): 4KB at Bp + s*8192 + nh*4096, ring slot s%6.
    const char* gB = (const char*)Bp + nh * 4096 + ln * 16;

#define STAGE(ring, sidx) do {                                                  \
        const char* _g = gB + (size_t)(sidx) * 8192;                            \
        char* _l = (char*)&BS[(ring)][0];                                       \
        GLOAD_LDS16(_g,        _l);                                             \
        GLOAD_LDS16(_g + 1024, _l + 1024);                                      \
        GLOAD_LDS16(_g + 2048, _l + 2048);                                      \
        GLOAD_LDS16(_g + 3072, _l + 3072);                                      \
    } while (0)

#define COMP(sidx, ring) do {                                                   \
        f16x8 bf0 = *(const f16x8*)&BS[(ring)][ln * 8];                         \
        f16x8 bf1 = *(const f16x8*)&BS[(ring)][512 + ln * 8];                   \
        f16x8 bf2 = *(const f16x8*)&BS[(ring)][1024 + ln * 8];                  \
        f16x8 bf3 = *(const f16x8*)&BS[(ring)][1536 + ln * 8];                  \
        _Pragma("unroll")                                                       \
        for (int ms = 0; ms < 4; ++ms) {                                        \
            f16 xv = xjS[ms * 16 + l15][(sidx)];                                \
            f16x8 xsp = {xv, xv, xv, xv, xv, xv, xv, xv};                       \
            f16x8 a0 = eav[ms][0] * xsp;                                        \
            f16x8 a1 = eav[ms][1] * xsp;                                        \
            acc[ms][0] = __builtin_amdgcn_mfma_f32_16x16x32_f16(a0, bf0, acc[ms][0], 0, 0, 0); \
            acc[ms][0] = __builtin_amdgcn_mfma_f32_16x16x32_f16(a1, bf1, acc[ms][0], 0, 0, 0); \
            acc[ms][1] = __builtin_amdgcn_mfma_f32_16x16x32_f16(a0, bf2, acc[ms][1], 0, 0, 0); \
            acc[ms][1] = __builtin_amdgcn_mfma_f32_16x16x32_f16(a1, bf3, acc[ms][1], 0, 0, 0); \
        }                                                                       \
    } while (0)

#define VWAIT(n) do { asm volatile("s_waitcnt vmcnt(" #n ")" ::: "memory");     \
                      __builtin_amdgcn_sched_barrier(0); } while (0)

    // Drain gathers, then fill 5 ring slots (20 loads in flight).
    asm volatile("s_waitcnt vmcnt(0)" ::: "memory");
    __builtin_amdgcn_sched_barrier(0);
    STAGE(0, 0); STAGE(1, 1); STAGE(2, 2); STAGE(3, 3); STAGE(4, 4);

    // Main loop: 60 stages, unrolled x6 so ring index is static.
#pragma unroll 1
    for (int s = 0; s < 60; s += 6) {
        VWAIT(16); COMP(s + 0, 0); STAGE(5, s + 5);
        VWAIT(16); COMP(s + 1, 1); STAGE(0, s + 6);
        VWAIT(16); COMP(s + 2, 2); STAGE(1, s + 7);
        VWAIT(16); COMP(s + 3, 3); STAGE(2, s + 8);
        VWAIT(16); COMP(s + 4, 4); STAGE(3, s + 9);
        VWAIT(16); COMP(s + 5, 5); STAGE(4, s + 10);
    }
    // Wait — the last loop iteration (s=54) issues stages up to s+10=64; but
    // iterations with s+6..s+10 > 64 would over-issue. 54+5=59..54+10=64: all
    // valid exactly at the final iteration; earlier iterations issue <=64. OK.
    // Tail: stages 60..64 already issued; outstanding = 20 loads.
    VWAIT(16); COMP(60, 0);
    VWAIT(12); COMP(61, 1);
    VWAIT(8);  COMP(62, 2);
    VWAIT(4);  COMP(63, 3);
    VWAIT(0);
    // bias stage (s=64, ring 4): A[e][i] = xj[e][i]
    {
        f16x8 bf0 = *(const f16x8*)&BS[4][ln * 8];
        f16x8 bf1 = *(const f16x8*)&BS[4][512 + ln * 8];
        f16x8 bf2 = *(const f16x8*)&BS[4][1024 + ln * 8];
        f16x8 bf3 = *(const f16x8*)&BS[4][1536 + ln * 8];
#pragma unroll
        for (int ms = 0; ms < 4; ++ms) {
            f16x8 af0 = *(const f16x8*)&xjS[ms * 16 + l15][l4 * 8];
            f16x8 af1 = *(const f16x8*)&xjS[ms * 16 + l15][32 + l4 * 8];
            acc[ms][0] = __builtin_amdgcn_mfma_f32_16x16x32_f16(af0, bf0, acc[ms][0], 0, 0, 0);
            acc[ms][0] = __builtin_amdgcn_mfma_f32_16x16x32_f16(af1, bf1, acc[ms][0], 0, 0, 0);
            acc[ms][1] = __builtin_amdgcn_mfma_f32_16x16x32_f16(af0, bf2, acc[ms][1], 0, 0, 0);
            acc[ms][1] = __builtin_amdgcn_mfma_f32_16x16x32_f16(af1, bf3, acc[ms][1], 0, 0, 0);
        }
    }

    // Plain coalesced stores at sorted position, col block nh*32.
#pragma unroll
    for (int ms = 0; ms < 4; ++ms)
#pragma unroll
        for (int q = 0; q < 4; ++q) {
            int p = e0 + ms * 16 + l4 * 4 + q;
            if (p < NEDGES) {
                float* row = msg + (size_t)p * CH + nh * 32;
                row[l15]      = acc[ms][0][q];
                row[16 + l15] = acc[ms][1][q];
            }
        }
#undef STAGE
#undef COMP
#undef VWAIT
}

// ---- fused root + bias + contiguous segment reduce (+ optional final) ----
//  acc[n][o] = bias[o] + sum_k act(x[n][k])*lw[k][o] + sum_{p in seg(n)} msg[p][o]
//  FINAL: outb[n][o] = relu(acc[n]) @ fin_w[.][o] + fin_b[o]
template<bool RELU_IN, bool FINAL>
__global__ __launch_bounds__(256)
void rootreduce_kernel(const float* __restrict__ x,
                       const float* __restrict__ lw,
                       const float* __restrict__ bias,
                       const float* __restrict__ msg,
                       const int* __restrict__ start,
                       const float* __restrict__ fw,
                       const float* __restrict__ fb,
                       float* __restrict__ outb) {
    __shared__ float vrow[4][64];
    int o  = threadIdx.x & 63;
    int wv = threadIdx.x >> 6;
    int gw = (blockIdx.x * 256 + threadIdx.x) >> 6;
    float lwc[64];
#pragma unroll
    for (int k = 0; k < 64; ++k) lwc[k] = lw[k * 64 + o];
    float fwc[64];
    float fbo = 0.f;
    if (FINAL) {
#pragma unroll
        for (int k = 0; k < 64; ++k) fwc[k] = fw[k * 64 + o];
        fbo = fb[o];
    }
    float bo = bias[o];
    for (int n = gw; n < NNODES; n += 1024) {
        const float4* xr = (const float4*)(x + (size_t)n * 64);
        float acc = bo;
#pragma unroll
        for (int kq = 0; kq < 16; ++kq) {
            float4 xv = xr[kq];
            float a = xv.x, b = xv.y, c = xv.z, d = xv.w;
            if (RELU_IN) {
                a = fmaxf(a, 0.f); b = fmaxf(b, 0.f);
                c = fmaxf(c, 0.f); d = fmaxf(d, 0.f);
            }
            acc = fmaf(a, lwc[kq * 4 + 0], acc);
            acc = fmaf(b, lwc[kq * 4 + 1], acc);
            acc = fmaf(c, lwc[kq * 4 + 2], acc);
            acc = fmaf(d, lwc[kq * 4 + 3], acc);
        }
        int pb = start[n], pe = start[n + 1];
        int p = pb;
        for (; p + 4 <= pe; p += 4) {   // 4 independent loads per batch
            float v0 = msg[(size_t)(p + 0) * 64 + o];
            float v1 = msg[(size_t)(p + 1) * 64 + o];
            float v2 = msg[(size_t)(p + 2) * 64 + o];
            float v3 = msg[(size_t)(p + 3) * 64 + o];
            acc += (v0 + v1) + (v2 + v3);
        }
        for (; p < pe; ++p)
            acc += msg[(size_t)p * 64 + o];
        if (FINAL) {
            vrow[wv][o] = fmaxf(acc, 0.f);   // wave-private row (in-order LDS)
            float a2 = fbo;
#pragma unroll
            for (int k = 0; k < 64; ++k)
                a2 = fmaf(vrow[wv][k], fwc[k], a2);
            outb[(size_t)n * 64 + o] = a2;
        } else {
            outb[(size_t)n * 64 + o] = acc;
        }
    }
}

extern "C" void kernel_launch(void* const* d_in, const int* in_sizes, int n_in,
                              void* d_out, int out_size, void* d_ws, size_t ws_size,
                              hipStream_t stream) {
    const float* feature = (const float*)d_in[0];
    const int*   ei      = (const int*)d_in[1];
    const float* ea      = (const float*)d_in[2];
    const float* nn_w0   = (const float*)d_in[3];
    const float* nn_b0   = (const float*)d_in[4];
    const float* lin_w0  = (const float*)d_in[5];
    const float* bias0   = (const float*)d_in[6];
    const float* nn_w1   = (const float*)d_in[7];
    const float* nn_b1   = (const float*)d_in[8];
    const float* lin_w1  = (const float*)d_in[9];
    const float* bias1   = (const float*)d_in[10];
    const float* fin_w   = (const float*)d_in[11];
    const float* fin_b   = (const float*)d_in[12];
    float* out = (float*)d_out;

    char* ws = (char*)d_ws;
    float* buf0   = (float*)(ws + 0);                 //  2,560,000
    f16*   Bp0    = (f16*)  (ws + 2560000);           //    532,480
    f16*   Bp1    = (f16*)  (ws + 3092480);           //    532,480
    int*   hist   = (int*)  (ws + 3624960);           //     40,000
    int*   cursor = (int*)  (ws + 3664960);           //     40,000
    int*   startp = (int*)  (ws + 3704960);           //     40,016
    int*   eperm  = (int*)  (ws + 3744976);           //    200,000
    int*   esrc   = (int*)  (ws + 3944976);           //    200,000
    float* eas    = (float*)(ws + 4144976);           // 12,800,000
    float* msg    = (float*)(ws + 16944976);          // 12,800,000 (end ~29.7MB)

    // dst-sorted CSR + sorted ea
    hipMemsetAsync(hist, 0, NNODES * sizeof(int), stream);
    hipMemsetAsync(cursor, 0, NNODES * sizeof(int), stream);
    hist_kernel<<<(NEDGES + 255) / 256, 256, 0, stream>>>(ei, hist);
    scan_kernel<<<1, 1024, 0, stream>>>(hist, startp);
    perm_kernel<<<(NEDGES + 255) / 256, 256, 0, stream>>>(ei, startp, cursor, eperm, esrc);
    eagather_kernel<<<(NEDGES * 16 + 255) / 256, 256, 0, stream>>>(ea, eperm, eas);

    // pack both layers' B
    pack_b_kernel<<<(2 * NSTAGES * 2048 + 255) / 256, 256, 0, stream>>>(
        nn_w0, nn_b0, nn_w1, nn_b1, Bp0, Bp1);

    dim3 eg((NEDGES + MW - 1) / MW, 2);   // 782 x 2 one-wave blocks

    // layer 0
    edge_gemm_kernel<false><<<eg, 64, 0, stream>>>(feature, esrc, eas, Bp0, msg);
    rootreduce_kernel<false, false><<<256, 256, 0, stream>>>(
        feature, lin_w0, bias0, msg, startp, fin_w, fin_b, buf0);
    // layer 1 (ReLU fused into loads) + final linear fused
    edge_gemm_kernel<true><<<eg, 64, 0, stream>>>(buf0, esrc, eas, Bp1, msg);
    rootreduce_kernel<true, true><<<256, 256, 0, stream>>>(
        buf0, lin_w1, bias1, msg, startp, fin_w, fin_b, out);
}

// Round 14
// 187.154 us; speedup vs baseline: 1.1049x; 1.1049x over previous
//
#include <hip/hip_runtime.h>

// MPNN (NNConv x2 + final linear) on MI355X — sorted-stream edge GEMM,
// 4-way O-split, register B-ring (4-deep, 2 loads/stage, counted vmcnt).
// msg[p] = Z @ B at dst-sorted position p; Z[p, i*64+k] = x[esrc[p],i]*eas[p,k].
// 1-wave blocks: 64 edges x 16 cols (blockIdx.y = col quarter). Grid 3128
// waves ~ 3 waves/SIMD: occupancy hides MFMA+load latency; no barriers.
// Reduce: contiguous segment sum + fused root linear (+ final linear on L1).

#define NNODES 10000
#define NEDGES 50000
#define CH 64
#define NSTAGES 65     // 64 i-stages + 1 bias stage
#define MW 64          // edges per wave

typedef _Float16 f16;
typedef f16 f16x8 __attribute__((ext_vector_type(8)));
typedef float f32x4 __attribute__((ext_vector_type(4)));

// ---------------- sorting (dst-order CSR) ----------------

__global__ void hist_kernel(const int* __restrict__ ei, int* __restrict__ hist) {
    int e = blockIdx.x * 256 + threadIdx.x;
    if (e < NEDGES) atomicAdd(&hist[ei[NEDGES + e]], 1);
}

__global__ __launch_bounds__(1024)
void scan_kernel(const int* __restrict__ hist, int* __restrict__ start) {
    __shared__ int buf[1024];
    int t = threadIdx.x;
    int base = t * 10;
    int loc[10];
    int s = 0;
#pragma unroll
    for (int i = 0; i < 10; ++i) {
        int n = base + i;
        int v = (n < NNODES) ? hist[n] : 0;
        loc[i] = s; s += v;
    }
    buf[t] = s;
    __syncthreads();
    for (int off = 1; off < 1024; off <<= 1) {
        int add = (t >= off) ? buf[t - off] : 0;
        __syncthreads();
        buf[t] += add;
        __syncthreads();
    }
    int ebase = buf[t] - s;
#pragma unroll
    for (int i = 0; i < 10; ++i) {
        int n = base + i;
        if (n < NNODES) start[n] = ebase + loc[i];
    }
    if (t == 1023) start[NNODES] = buf[1023];
}

__global__ void perm_kernel(const int* __restrict__ ei,
                            const int* __restrict__ start,
                            int* __restrict__ cursor,
                            int* __restrict__ eperm,
                            int* __restrict__ esrc) {
    int e = blockIdx.x * 256 + threadIdx.x;
    if (e < NEDGES) {
        int d = ei[NEDGES + e];
        int pos = start[d] + atomicAdd(&cursor[d], 1);
        eperm[pos] = e;
        esrc[pos]  = ei[e];
    }
}

// eas[p][c] = ea[eperm[p]][c]  (sorted ea rows)
__global__ void eagather_kernel(const float* __restrict__ ea,
                                const int* __restrict__ eperm,
                                float* __restrict__ eas) {
    int idx = blockIdx.x * 256 + threadIdx.x;
    if (idx >= NEDGES * 16) return;
    int p = idx >> 4, quad = idx & 15;
    int e = eperm[p];
    *(float4*)(eas + (size_t)p * 64 + quad * 4) =
        *(const float4*)(ea + (size_t)e * 64 + quad * 4);
}

// ---------------- B packing (fragment-major, both layers) ----------------
// frag id f = (s*8 + q2)*64 + ln  (q2 = tn*2+h), 16B each:
//   col = tn*16 + (ln&15), koff = h*32 + (ln>>4)*8 + j, j=0..7
//   s<64:  nn_w[koff*4096 + s*64 + col] ; s==64: nn_b[koff*64 + col]
__global__ void pack_b_kernel(const float* __restrict__ nw0, const float* __restrict__ nb0,
                              const float* __restrict__ nw1, const float* __restrict__ nb1,
                              f16* __restrict__ Bp0, f16* __restrict__ Bp1) {
    int idx = blockIdx.x * 256 + threadIdx.x;
    if (idx >= 2 * NSTAGES * 2048) return;
    int layer = (idx >= NSTAGES * 2048) ? 1 : 0;
    int r = idx - layer * NSTAGES * 2048;
    const float* nn_w = layer ? nw1 : nw0;
    const float* nn_b = layer ? nb1 : nb0;
    f16* Bp = layer ? Bp1 : Bp0;
    int p  = r & 3;
    int f  = r >> 2;
    int ln = f & 63;
    int q2 = (f >> 6) & 7;
    int s  = f >> 9;
    int tn = q2 >> 1, h = q2 & 1;
    int col  = tn * 16 + (ln & 15);
    int koff = h * 32 + (ln >> 4) * 8 + p * 2;
    float v0, v1;
    if (s < 64) {
        v0 = nn_w[(size_t)koff * 4096 + s * 64 + col];
        v1 = nn_w[(size_t)(koff + 1) * 4096 + s * 64 + col];
    } else {
        v0 = nn_b[koff * 64 + col];
        v1 = nn_b[(koff + 1) * 64 + col];
    }
    union { f16 h2[2]; unsigned u; } pk;
    pk.h2[0] = (f16)v0; pk.h2[1] = (f16)v1;
    *(unsigned*)((char*)Bp + (size_t)f * 16 + p * 4) = pk.u;
}

// ---- edge GEMM: 1 wave, 64 sorted edges x 16 cols (by = col quarter) ----
template<bool RELU_IN>
__global__ __launch_bounds__(64, 4)
void edge_gemm_kernel(const float* __restrict__ x,
                      const int* __restrict__ esrc,   // sorted src ids
                      const float* __restrict__ eas,  // sorted ea rows
                      const f16* __restrict__ Bp,     // fragment-major
                      float* __restrict__ msg) {      // [E][64] at sorted pos
    __shared__ f16 xjS[MW][72];                       // 9,216 B

    int ln  = threadIdx.x;
    int l15 = ln & 15, l4 = ln >> 4;
    int e0  = blockIdx.x * MW;
    int nh  = blockIdx.y;          // col quarter 0..3

    // Gather x[src] rows (fused ReLU) into LDS as f16: 64 edges x 16 float4.
#pragma unroll
    for (int r = 0; r < 16; ++r) {
        int idx = r * 64 + ln;
        int el = idx >> 4, ip = idx & 15;
        int p  = e0 + el;
        float4 v = {0.f, 0.f, 0.f, 0.f};
        if (p < NEDGES)
            v = *(const float4*)(x + (size_t)esrc[p] * CH + ip * 4);
        if (RELU_IN) {
            v.x = fmaxf(v.x, 0.f); v.y = fmaxf(v.y, 0.f);
            v.z = fmaxf(v.z, 0.f); v.w = fmaxf(v.w, 0.f);
        }
        union { f16 h4[4]; uint2 u; } pk;
        pk.h4[0] = (f16)v.x; pk.h4[1] = (f16)v.y;
        pk.h4[2] = (f16)v.z; pk.h4[3] = (f16)v.w;
        *(uint2*)&xjS[el][ip * 4] = pk.u;
    }

    // ea fragments (stage-invariant): 4 m-tiles x 2 halves, contiguous rows
    f16x8 eav[4][2];
#pragma unroll
    for (int ms = 0; ms < 4; ++ms) {
        int p = e0 + ms * 16 + l15;
#pragma unroll
        for (int h = 0; h < 2; ++h) {
            float4 a = {0.f,0.f,0.f,0.f}, b = {0.f,0.f,0.f,0.f};
            if (p < NEDGES) {
                const float4* q = (const float4*)(eas + (size_t)p * CH + h * 32 + l4 * 8);
                a = q[0]; b = q[1];
            }
            f16x8 f;
            f[0]=(f16)a.x; f[1]=(f16)a.y; f[2]=(f16)a.z; f[3]=(f16)a.w;
            f[4]=(f16)b.x; f[5]=(f16)b.y; f[6]=(f16)b.z; f[7]=(f16)b.w;
            eav[ms][h] = f;
        }
    }

    f32x4 acc[4];
#pragma unroll
    for (int ms = 0; ms < 4; ++ms)
        acc[ms] = (f32x4){0.f, 0.f, 0.f, 0.f};

    // B stage s, quarter nh: 2KB at Bp + s*8192 + nh*2048 (h=0/1 at +0/+1024).
    const char* gB = (const char*)Bp + nh * 2048 + ln * 16;

#define LOADB(b, sidx) do {                                                     \
        const char* _p = gB + (size_t)(sidx) * 8192;                            \
        b[0] = *(const f16x8*)(_p);                                             \
        b[1] = *(const f16x8*)(_p + 1024);                                      \
    } while (0)

#define COMP(sidx, b) do {                                                      \
        _Pragma("unroll")                                                       \
        for (int ms = 0; ms < 4; ++ms) {                                        \
            f16 xv = xjS[ms * 16 + l15][(sidx)];                                \
            f16x8 xsp = {xv, xv, xv, xv, xv, xv, xv, xv};                       \
            f16x8 a0 = eav[ms][0] * xsp;                                        \
            f16x8 a1 = eav[ms][1] * xsp;                                        \
            acc[ms] = __builtin_amdgcn_mfma_f32_16x16x32_f16(a0, b[0], acc[ms], 0, 0, 0); \
            acc[ms] = __builtin_amdgcn_mfma_f32_16x16x32_f16(a1, b[1], acc[ms], 0, 0, 0); \
        }                                                                       \
    } while (0)

#define VWAIT(n) do { asm volatile("s_waitcnt vmcnt(" #n ")" ::: "memory");     \
                      __builtin_amdgcn_sched_barrier(0); } while (0)

    f16x8 b0[2], b1[2], b2[2], b3[2];
    // Drain gather/eav, then fill the 4-deep ring (8 loads in flight).
    asm volatile("s_waitcnt vmcnt(0)" ::: "memory");
    __builtin_amdgcn_sched_barrier(0);
    LOADB(b0, 0); LOADB(b1, 1); LOADB(b2, 2); LOADB(b3, 3);

#pragma unroll 1
    for (int s = 0; s <= 56; s += 4) {
        VWAIT(6); COMP(s,     b0); LOADB(b0, s + 4);
        VWAIT(6); COMP(s + 1, b1); LOADB(b1, s + 5);
        VWAIT(6); COMP(s + 2, b2); LOADB(b2, s + 6);
        VWAIT(6); COMP(s + 3, b3); LOADB(b3, s + 7);
    }
    // Comped 0..59; issued through stage 63; outstanding = 8 (stages 60..63).
    VWAIT(6); COMP(60, b0); LOADB(b0, 64);   // bias-stage frags into b0
    VWAIT(6); COMP(61, b1);
    VWAIT(4); COMP(62, b2);
    VWAIT(2); COMP(63, b3);
    VWAIT(0);
    // bias stage (s=64): A[e][i] = xj[e][i], B = b0
#pragma unroll
    for (int ms = 0; ms < 4; ++ms) {
        f16x8 af0 = *(const f16x8*)&xjS[ms * 16 + l15][l4 * 8];
        f16x8 af1 = *(const f16x8*)&xjS[ms * 16 + l15][32 + l4 * 8];
        acc[ms] = __builtin_amdgcn_mfma_f32_16x16x32_f16(af0, b0[0], acc[ms], 0, 0, 0);
        acc[ms] = __builtin_amdgcn_mfma_f32_16x16x32_f16(af1, b0[1], acc[ms], 0, 0, 0);
    }

    // Plain coalesced stores at sorted position, col block nh*16.
#pragma unroll
    for (int ms = 0; ms < 4; ++ms)
#pragma unroll
        for (int q = 0; q < 4; ++q) {
            int p = e0 + ms * 16 + l4 * 4 + q;
            if (p < NEDGES)
                msg[(size_t)p * CH + nh * 16 + l15] = acc[ms][q];
        }
#undef LOADB
#undef COMP
#undef VWAIT
}

// ---- fused root + bias + contiguous segment reduce (+ optional final) ----
template<bool RELU_IN, bool FINAL>
__global__ __launch_bounds__(256)
void rootreduce_kernel(const float* __restrict__ x,
                       const float* __restrict__ lw,
                       const float* __restrict__ bias,
                       const float* __restrict__ msg,
                       const int* __restrict__ start,
                       const float* __restrict__ fw,
                       const float* __restrict__ fb,
                       float* __restrict__ outb) {
    __shared__ float vrow[4][64];
    int o  = threadIdx.x & 63;
    int wv = threadIdx.x >> 6;
    int gw = (blockIdx.x * 256 + threadIdx.x) >> 6;
    float lwc[64];
#pragma unroll
    for (int k = 0; k < 64; ++k) lwc[k] = lw[k * 64 + o];
    float fwc[64];
    float fbo = 0.f;
    if (FINAL) {
#pragma unroll
        for (int k = 0; k < 64; ++k) fwc[k] = fw[k * 64 + o];
        fbo = fb[o];
    }
    float bo = bias[o];
    for (int n = gw; n < NNODES; n += 1024) {
        const float4* xr = (const float4*)(x + (size_t)n * 64);
        float acc = bo;
#pragma unroll
        for (int kq = 0; kq < 16; ++kq) {
            float4 xv = xr[kq];
            float a = xv.x, b = xv.y, c = xv.z, d = xv.w;
            if (RELU_IN) {
                a = fmaxf(a, 0.f); b = fmaxf(b, 0.f);
                c = fmaxf(c, 0.f); d = fmaxf(d, 0.f);
            }
            acc = fmaf(a, lwc[kq * 4 + 0], acc);
            acc = fmaf(b, lwc[kq * 4 + 1], acc);
            acc = fmaf(c, lwc[kq * 4 + 2], acc);
            acc = fmaf(d, lwc[kq * 4 + 3], acc);
        }
        int pb = start[n], pe = start[n + 1];
        int p = pb;
        for (; p + 4 <= pe; p += 4) {
            float v0 = msg[(size_t)(p + 0) * 64 + o];
            float v1 = msg[(size_t)(p + 1) * 64 + o];
            float v2 = msg[(size_t)(p + 2) * 64 + o];
            float v3 = msg[(size_t)(p + 3) * 64 + o];
            acc += (v0 + v1) + (v2 + v3);
        }
        for (; p < pe; ++p)
            acc += msg[(size_t)p * 64 + o];
        if (FINAL) {
            vrow[wv][o] = fmaxf(acc, 0.f);
            float a2 = fbo;
#pragma unroll
            for (int k = 0; k < 64; ++k)
                a2 = fmaf(vrow[wv][k], fwc[k], a2);
            outb[(size_t)n * 64 + o] = a2;
        } else {
            outb[(size_t)n * 64 + o] = acc;
        }
    }
}

extern "C" void kernel_launch(void* const* d_in, const int* in_sizes, int n_in,
                              void* d_out, int out_size, void* d_ws, size_t ws_size,
                              hipStream_t stream) {
    const float* feature = (const float*)d_in[0];
    const int*   ei      = (const int*)d_in[1];
    const float* ea      = (const float*)d_in[2];
    const float* nn_w0   = (const float*)d_in[3];
    const float* nn_b0   = (const float*)d_in[4];
    const float* lin_w0  = (const float*)d_in[5];
    const float* bias0   = (const float*)d_in[6];
    const float* nn_w1   = (const float*)d_in[7];
    const float* nn_b1   = (const float*)d_in[8];
    const float* lin_w1  = (const float*)d_in[9];
    const float* bias1   = (const float*)d_in[10];
    const float* fin_w   = (const float*)d_in[11];
    const float* fin_b   = (const float*)d_in[12];
    float* out = (float*)d_out;

    char* ws = (char*)d_ws;
    float* buf0   = (float*)(ws + 0);                 //  2,560,000
    f16*   Bp0    = (f16*)  (ws + 2560000);           //    532,480
    f16*   Bp1    = (f16*)  (ws + 3092480);           //    532,480
    int*   hist   = (int*)  (ws + 3624960);           //     40,000
    int*   cursor = (int*)  (ws + 3664960);           //     40,000
    int*   startp = (int*)  (ws + 3704960);           //     40,016
    int*   eperm  = (int*)  (ws + 3744976);           //    200,000
    int*   esrc   = (int*)  (ws + 3944976);           //    200,000
    float* eas    = (float*)(ws + 4144976);           // 12,800,000
    float* msg    = (float*)(ws + 16944976);          // 12,800,000 (end ~29.7MB)

    // dst-sorted CSR + sorted ea
    hipMemsetAsync(hist, 0, NNODES * sizeof(int), stream);
    hipMemsetAsync(cursor, 0, NNODES * sizeof(int), stream);
    hist_kernel<<<(NEDGES + 255) / 256, 256, 0, stream>>>(ei, hist);
    scan_kernel<<<1, 1024, 0, stream>>>(hist, startp);
    perm_kernel<<<(NEDGES + 255) / 256, 256, 0, stream>>>(ei, startp, cursor, eperm, esrc);
    eagather_kernel<<<(NEDGES * 16 + 255) / 256, 256, 0, stream>>>(ea, eperm, eas);

    // pack both layers' B
    pack_b_kernel<<<(2 * NSTAGES * 2048 + 255) / 256, 256, 0, stream>>>(
        nn_w0, nn_b0, nn_w1, nn_b1, Bp0, Bp1);

    dim3 eg((NEDGES + MW - 1) / MW, 4);   // 782 x 4 one-wave blocks

    // layer 0
    edge_gemm_kernel<false><<<eg, 64, 0, stream>>>(feature, esrc, eas, Bp0, msg);
    rootreduce_kernel<false, false><<<256, 256, 0, stream>>>(
        feature, lin_w0, bias0, msg, startp, fin_w, fin_b, buf0);
    // layer 1 (ReLU fused into loads) + final linear fused
    edge_gemm_kernel<true><<<eg, 64, 0, stream>>>(buf0, esrc, eas, Bp1, msg);
    rootreduce_kernel<true, true><<<256, 256, 0, stream>>>(
        buf0, lin_w1, bias1, msg, startp, fin_w, fin_b, out);
}

// Round 15
// 166.056 us; speedup vs baseline: 1.2453x; 1.1271x over previous
//
#include <hip/hip_runtime.h>

// MPNN (NNConv x2 + final linear) on MI355X — consolidation round:
// R12's proven edge GEMM (sorted stream, O-split 2, register triple-buffer,
// counted vmcnt(8)) + R13's proven aux set (memsets, fused final) + perm/ea merge.
// msg[p] = Z @ B at dst-sorted position p; Z[p, i*64+k] = x[esrc[p],i]*eas[p,k].

#define NNODES 10000
#define NEDGES 50000
#define CH 64
#define NSTAGES 65     // 64 i-stages + 1 bias stage
#define MW 64          // edges per wave

typedef _Float16 f16;
typedef f16 f16x8 __attribute__((ext_vector_type(8)));
typedef float f32x4 __attribute__((ext_vector_type(4)));

// ---------------- sorting (dst-order CSR) ----------------

__global__ void hist_kernel(const int* __restrict__ ei, int* __restrict__ hist) {
    int e = blockIdx.x * 256 + threadIdx.x;
    if (e < NEDGES) atomicAdd(&hist[ei[NEDGES + e]], 1);
}

__global__ __launch_bounds__(1024)
void scan_kernel(const int* __restrict__ hist, int* __restrict__ start) {
    __shared__ int buf[1024];
    int t = threadIdx.x;
    int base = t * 10;
    int loc[10];
    int s = 0;
#pragma unroll
    for (int i = 0; i < 10; ++i) {
        int n = base + i;
        int v = (n < NNODES) ? hist[n] : 0;
        loc[i] = s; s += v;
    }
    buf[t] = s;
    __syncthreads();
    for (int off = 1; off < 1024; off <<= 1) {
        int add = (t >= off) ? buf[t - off] : 0;
        __syncthreads();
        buf[t] += add;
        __syncthreads();
    }
    int ebase = buf[t] - s;
#pragma unroll
    for (int i = 0; i < 10; ++i) {
        int n = base + i;
        if (n < NNODES) start[n] = ebase + loc[i];
    }
    if (t == 1023) start[NNODES] = buf[1023];
}

// perm: compute sorted position, record src id, and copy the ea row to its
// sorted slot (replaces the separate eagather pass; eperm no longer needed).
__global__ void perm_kernel(const int* __restrict__ ei,
                            const int* __restrict__ start,
                            int* __restrict__ cursor,
                            int* __restrict__ esrc,
                            const float* __restrict__ ea,
                            float* __restrict__ eas) {
    int e = blockIdx.x * 256 + threadIdx.x;
    if (e < NEDGES) {
        int d = ei[NEDGES + e];
        int pos = start[d] + atomicAdd(&cursor[d], 1);
        esrc[pos] = ei[e];
        const float4* src = (const float4*)(ea + (size_t)e * 64);
        float4* dst = (float4*)(eas + (size_t)pos * 64);
#pragma unroll
        for (int q = 0; q < 16; ++q) dst[q] = src[q];
    }
}

// ---------------- B packing (fragment-major, both layers) ----------------
// frag id f = (s*8 + q2)*64 + ln  (q2 = tn*2+h), 16B each:
//   col = tn*16 + (ln&15), koff = h*32 + (ln>>4)*8 + j, j=0..7
//   s<64:  nn_w[koff*4096 + s*64 + col] ; s==64: nn_b[koff*64 + col]
__global__ void pack_b_kernel(const float* __restrict__ nw0, const float* __restrict__ nb0,
                              const float* __restrict__ nw1, const float* __restrict__ nb1,
                              f16* __restrict__ Bp0, f16* __restrict__ Bp1) {
    int idx = blockIdx.x * 256 + threadIdx.x;
    if (idx >= 2 * NSTAGES * 2048) return;
    int layer = (idx >= NSTAGES * 2048) ? 1 : 0;
    int r = idx - layer * NSTAGES * 2048;
    const float* nn_w = layer ? nw1 : nw0;
    const float* nn_b = layer ? nb1 : nb0;
    f16* Bp = layer ? Bp1 : Bp0;
    int p  = r & 3;
    int f  = r >> 2;
    int ln = f & 63;
    int q2 = (f >> 6) & 7;
    int s  = f >> 9;
    int tn = q2 >> 1, h = q2 & 1;
    int col  = tn * 16 + (ln & 15);
    int koff = h * 32 + (ln >> 4) * 8 + p * 2;
    float v0, v1;
    if (s < 64) {
        v0 = nn_w[(size_t)koff * 4096 + s * 64 + col];
        v1 = nn_w[(size_t)(koff + 1) * 4096 + s * 64 + col];
    } else {
        v0 = nn_b[koff * 64 + col];
        v1 = nn_b[(koff + 1) * 64 + col];
    }
    union { f16 h2[2]; unsigned u; } pk;
    pk.h2[0] = (f16)v0; pk.h2[1] = (f16)v1;
    *(unsigned*)((char*)Bp + (size_t)f * 16 + p * 4) = pk.u;
}

// ------- edge GEMM: 1 wave, 64 sorted edges x 32 cols (by = col half) -------
// (exact R12 structure — measured 44.5 us, absmax 4.0)
template<bool RELU_IN>
__global__ __launch_bounds__(64, 2)
void edge_gemm_kernel(const float* __restrict__ x,
                      const int* __restrict__ esrc,   // sorted src ids
                      const float* __restrict__ eas,  // sorted ea rows
                      const f16* __restrict__ Bp,     // fragment-major
                      float* __restrict__ msg) {      // [E][64] at sorted pos
    __shared__ f16 xjS[MW][72];

    int ln  = threadIdx.x;
    int l15 = ln & 15, l4 = ln >> 4;
    int e0  = blockIdx.x * MW;
    int nh  = blockIdx.y;          // col half 0/1

    // Gather x[src] rows (fused ReLU) into LDS as f16: 64 edges x 16 float4.
#pragma unroll
    for (int r = 0; r < 16; ++r) {
        int idx = r * 64 + ln;
        int el = idx >> 4, ip = idx & 15;
        int p  = e0 + el;
        float4 v = {0.f, 0.f, 0.f, 0.f};
        if (p < NEDGES)
            v = *(const float4*)(x + (size_t)esrc[p] * CH + ip * 4);
        if (RELU_IN) {
            v.x = fmaxf(v.x, 0.f); v.y = fmaxf(v.y, 0.f);
            v.z = fmaxf(v.z, 0.f); v.w = fmaxf(v.w, 0.f);
        }
        union { f16 h4[4]; uint2 u; } pk;
        pk.h4[0] = (f16)v.x; pk.h4[1] = (f16)v.y;
        pk.h4[2] = (f16)v.z; pk.h4[3] = (f16)v.w;
        *(uint2*)&xjS[el][ip * 4] = pk.u;
    }

    // ea fragments (stage-invariant): 4 m-tiles x 2 halves, contiguous rows
    f16x8 eav[4][2];
#pragma unroll
    for (int ms = 0; ms < 4; ++ms) {
        int p = e0 + ms * 16 + l15;
#pragma unroll
        for (int h = 0; h < 2; ++h) {
            float4 a = {0.f,0.f,0.f,0.f}, b = {0.f,0.f,0.f,0.f};
            if (p < NEDGES) {
                const float4* q = (const float4*)(eas + (size_t)p * CH + h * 32 + l4 * 8);
                a = q[0]; b = q[1];
            }
            f16x8 f;
            f[0]=(f16)a.x; f[1]=(f16)a.y; f[2]=(f16)a.z; f[3]=(f16)a.w;
            f[4]=(f16)b.x; f[5]=(f16)b.y; f[6]=(f16)b.z; f[7]=(f16)b.w;
            eav[ms][h] = f;
        }
    }

    f32x4 acc[4][2];
#pragma unroll
    for (int ms = 0; ms < 4; ++ms)
#pragma unroll
        for (int tl = 0; tl < 2; ++tl)
            acc[ms][tl] = (f32x4){0.f, 0.f, 0.f, 0.f};

    const char* gB = (const char*)Bp + nh * 4096 + ln * 16;

#define LOADB(b, sidx) do {                                                     \
        const char* _p = gB + (size_t)(sidx) * 8192;                            \
        b[0] = *(const f16x8*)(_p);                                             \
        b[1] = *(const f16x8*)(_p + 1024);                                      \
        b[2] = *(const f16x8*)(_p + 2048);                                      \
        b[3] = *(const f16x8*)(_p + 3072);                                      \
    } while (0)

#define COMP(sidx, b) do {                                                      \
        _Pragma("unroll")                                                       \
        for (int ms = 0; ms < 4; ++ms) {                                        \
            f16 xv = xjS[ms * 16 + l15][(sidx)];                                \
            f16x8 xsp = {xv, xv, xv, xv, xv, xv, xv, xv};                       \
            f16x8 a0 = eav[ms][0] * xsp;                                        \
            f16x8 a1 = eav[ms][1] * xsp;                                        \
            _Pragma("unroll")                                                   \
            for (int tl = 0; tl < 2; ++tl) {                                    \
                acc[ms][tl] = __builtin_amdgcn_mfma_f32_16x16x32_f16(a0, b[tl*2+0], acc[ms][tl], 0, 0, 0); \
                acc[ms][tl] = __builtin_amdgcn_mfma_f32_16x16x32_f16(a1, b[tl*2+1], acc[ms][tl], 0, 0, 0); \
            }                                                                   \
        }                                                                       \
    } while (0)

#define WAIT8 do { asm volatile("s_waitcnt vmcnt(8)" ::: "memory");             \
                   __builtin_amdgcn_sched_barrier(0); } while (0)

    f16x8 b0[4], b1[4], b2[4];
    LOADB(b0, 0); LOADB(b1, 1); LOADB(b2, 2);
    asm volatile("s_waitcnt vmcnt(0)" ::: "memory");   // drain gathers + prologue
    __builtin_amdgcn_sched_barrier(0);

#pragma unroll 1
    for (int s = 0; s < 63; s += 3) {
        WAIT8; COMP(s,     b0); LOADB(b0, s + 3);
        WAIT8; COMP(s + 1, b1); LOADB(b1, s + 4);
        WAIT8; COMP(s + 2, b2); LOADB(b2, min(s + 5, 64));
    }
    // outstanding: b0(63), b1(64), b2(64dup) = 12 loads
    WAIT8;                                              // b0(63) landed
    COMP(63, b0);
    asm volatile("s_waitcnt vmcnt(4)" ::: "memory");    // b1(64) landed
    __builtin_amdgcn_sched_barrier(0);
    // bias stage: A[e][i] = xj[e][i], B = b1 (stage 64)
#pragma unroll
    for (int ms = 0; ms < 4; ++ms)
#pragma unroll
        for (int h = 0; h < 2; ++h) {
            f16x8 af = *(const f16x8*)&xjS[ms * 16 + l15][h * 32 + l4 * 8];
#pragma unroll
            for (int tl = 0; tl < 2; ++tl)
                acc[ms][tl] = __builtin_amdgcn_mfma_f32_16x16x32_f16(af, b1[tl * 2 + h], acc[ms][tl], 0, 0, 0);
        }

    // Plain coalesced stores at sorted position, col block nh*32.
#pragma unroll
    for (int ms = 0; ms < 4; ++ms)
#pragma unroll
        for (int q = 0; q < 4; ++q) {
            int p = e0 + ms * 16 + l4 * 4 + q;
            if (p < NEDGES) {
                float* row = msg + (size_t)p * CH + nh * 32;
                row[l15]      = acc[ms][0][q];
                row[16 + l15] = acc[ms][1][q];
            }
        }
#undef LOADB
#undef COMP
#undef WAIT8
}

// ---- fused root + bias + contiguous segment reduce (+ optional final) ----
template<bool RELU_IN, bool FINAL>
__global__ __launch_bounds__(256)
void rootreduce_kernel(const float* __restrict__ x,
                       const float* __restrict__ lw,
                       const float* __restrict__ bias,
                       const float* __restrict__ msg,
                       const int* __restrict__ start,
                       const float* __restrict__ fw,
                       const float* __restrict__ fb,
                       float* __restrict__ outb) {
    __shared__ float vrow[4][64];
    int o  = threadIdx.x & 63;
    int wv = threadIdx.x >> 6;
    int gw = (blockIdx.x * 256 + threadIdx.x) >> 6;
    float lwc[64];
#pragma unroll
    for (int k = 0; k < 64; ++k) lwc[k] = lw[k * 64 + o];
    float fwc[64];
    float fbo = 0.f;
    if (FINAL) {
#pragma unroll
        for (int k = 0; k < 64; ++k) fwc[k] = fw[k * 64 + o];
        fbo = fb[o];
    }
    float bo = bias[o];
    for (int n = gw; n < NNODES; n += 1024) {
        const float4* xr = (const float4*)(x + (size_t)n * 64);
        float acc = bo;
#pragma unroll
        for (int kq = 0; kq < 16; ++kq) {
            float4 xv = xr[kq];
            float a = xv.x, b = xv.y, c = xv.z, d = xv.w;
            if (RELU_IN) {
                a = fmaxf(a, 0.f); b = fmaxf(b, 0.f);
                c = fmaxf(c, 0.f); d = fmaxf(d, 0.f);
            }
            acc = fmaf(a, lwc[kq * 4 + 0], acc);
            acc = fmaf(b, lwc[kq * 4 + 1], acc);
            acc = fmaf(c, lwc[kq * 4 + 2], acc);
            acc = fmaf(d, lwc[kq * 4 + 3], acc);
        }
        int pb = start[n], pe = start[n + 1];
        int p = pb;
        for (; p + 4 <= pe; p += 4) {
            float v0 = msg[(size_t)(p + 0) * 64 + o];
            float v1 = msg[(size_t)(p + 1) * 64 + o];
            float v2 = msg[(size_t)(p + 2) * 64 + o];
            float v3 = msg[(size_t)(p + 3) * 64 + o];
            acc += (v0 + v1) + (v2 + v3);
        }
        for (; p < pe; ++p)
            acc += msg[(size_t)p * 64 + o];
        if (FINAL) {
            vrow[wv][o] = fmaxf(acc, 0.f);
            float a2 = fbo;
#pragma unroll
            for (int k = 0; k < 64; ++k)
                a2 = fmaf(vrow[wv][k], fwc[k], a2);
            outb[(size_t)n * 64 + o] = a2;
        } else {
            outb[(size_t)n * 64 + o] = acc;
        }
    }
}

extern "C" void kernel_launch(void* const* d_in, const int* in_sizes, int n_in,
                              void* d_out, int out_size, void* d_ws, size_t ws_size,
                              hipStream_t stream) {
    const float* feature = (const float*)d_in[0];
    const int*   ei      = (const int*)d_in[1];
    const float* ea      = (const float*)d_in[2];
    const float* nn_w0   = (const float*)d_in[3];
    const float* nn_b0   = (const float*)d_in[4];
    const float* lin_w0  = (const float*)d_in[5];
    const float* bias0   = (const float*)d_in[6];
    const float* nn_w1   = (const float*)d_in[7];
    const float* nn_b1   = (const float*)d_in[8];
    const float* lin_w1  = (const float*)d_in[9];
    const float* bias1   = (const float*)d_in[10];
    const float* fin_w   = (const float*)d_in[11];
    const float* fin_b   = (const float*)d_in[12];
    float* out = (float*)d_out;

    char* ws = (char*)d_ws;
    float* buf0   = (float*)(ws + 0);                 //  2,560,000
    f16*   Bp0    = (f16*)  (ws + 2560000);           //    532,480
    f16*   Bp1    = (f16*)  (ws + 3092480);           //    532,480
    int*   hist   = (int*)  (ws + 3624960);           //     40,000
    int*   cursor = (int*)  (ws + 3664960);           //     40,000
    int*   startp = (int*)  (ws + 3704960);           //     40,016
    int*   esrc   = (int*)  (ws + 3744976);           //    200,000
    float* eas    = (float*)(ws + 3944976);           // 12,800,000
    float* msg    = (float*)(ws + 16744976);          // 12,800,000 (end ~29.5MB)

    // dst-sorted CSR + sorted ea rows (merged into perm)
    hipMemsetAsync(hist, 0, NNODES * sizeof(int), stream);
    hipMemsetAsync(cursor, 0, NNODES * sizeof(int), stream);
    hist_kernel<<<(NEDGES + 255) / 256, 256, 0, stream>>>(ei, hist);
    scan_kernel<<<1, 1024, 0, stream>>>(hist, startp);
    perm_kernel<<<(NEDGES + 255) / 256, 256, 0, stream>>>(ei, startp, cursor,
                                                          esrc, ea, eas);

    // pack both layers' B
    pack_b_kernel<<<(2 * NSTAGES * 2048 + 255) / 256, 256, 0, stream>>>(
        nn_w0, nn_b0, nn_w1, nn_b1, Bp0, Bp1);

    dim3 eg((NEDGES + MW - 1) / MW, 2);   // 782 x 2 one-wave blocks

    // layer 0
    edge_gemm_kernel<false><<<eg, 64, 0, stream>>>(feature, esrc, eas, Bp0, msg);
    rootreduce_kernel<false, false><<<256, 256, 0, stream>>>(
        feature, lin_w0, bias0, msg, startp, fin_w, fin_b, buf0);
    // layer 1 (ReLU fused into loads) + final linear fused
    edge_gemm_kernel<true><<<eg, 64, 0, stream>>>(buf0, esrc, eas, Bp1, msg);
    rootreduce_kernel<true, true><<<256, 256, 0, stream>>>(
        buf0, lin_w1, bias1, msg, startp, fin_w, fin_b, out);
}

// Round 16
// 164.221 us; speedup vs baseline: 1.2592x; 1.0112x over previous
//
#include <hip/hip_runtime.h>

// MPNN (NNConv x2 + final linear) on MI355X — R15 frozen + 2 deltas:
// (1) hipMemsetAsync -> zero_kernel (fillBufferAligned showed 45us in profile)
// (2) s_setprio(1) around edge MFMA cluster (T5, 1-wave-block regime)

#define NNODES 10000
#define NEDGES 50000
#define CH 64
#define NSTAGES 65     // 64 i-stages + 1 bias stage
#define MW 64          // edges per wave

typedef _Float16 f16;
typedef f16 f16x8 __attribute__((ext_vector_type(8)));
typedef float f32x4 __attribute__((ext_vector_type(4)));

// ---------------- sorting (dst-order CSR) ----------------

__global__ void zero_kernel(int* __restrict__ hist, int* __restrict__ cursor) {
    int idx = blockIdx.x * 256 + threadIdx.x;
    if (idx < NNODES) { hist[idx] = 0; cursor[idx] = 0; }
}

__global__ void hist_kernel(const int* __restrict__ ei, int* __restrict__ hist) {
    int e = blockIdx.x * 256 + threadIdx.x;
    if (e < NEDGES) atomicAdd(&hist[ei[NEDGES + e]], 1);
}

__global__ __launch_bounds__(1024)
void scan_kernel(const int* __restrict__ hist, int* __restrict__ start) {
    __shared__ int buf[1024];
    int t = threadIdx.x;
    int base = t * 10;
    int loc[10];
    int s = 0;
#pragma unroll
    for (int i = 0; i < 10; ++i) {
        int n = base + i;
        int v = (n < NNODES) ? hist[n] : 0;
        loc[i] = s; s += v;
    }
    buf[t] = s;
    __syncthreads();
    for (int off = 1; off < 1024; off <<= 1) {
        int add = (t >= off) ? buf[t - off] : 0;
        __syncthreads();
        buf[t] += add;
        __syncthreads();
    }
    int ebase = buf[t] - s;
#pragma unroll
    for (int i = 0; i < 10; ++i) {
        int n = base + i;
        if (n < NNODES) start[n] = ebase + loc[i];
    }
    if (t == 1023) start[NNODES] = buf[1023];
}

// perm: compute sorted position, record src id, and copy the ea row to its
// sorted slot (merged eagather; eperm not needed).
__global__ void perm_kernel(const int* __restrict__ ei,
                            const int* __restrict__ start,
                            int* __restrict__ cursor,
                            int* __restrict__ esrc,
                            const float* __restrict__ ea,
                            float* __restrict__ eas) {
    int e = blockIdx.x * 256 + threadIdx.x;
    if (e < NEDGES) {
        int d = ei[NEDGES + e];
        int pos = start[d] + atomicAdd(&cursor[d], 1);
        esrc[pos] = ei[e];
        const float4* src = (const float4*)(ea + (size_t)e * 64);
        float4* dst = (float4*)(eas + (size_t)pos * 64);
#pragma unroll
        for (int q = 0; q < 16; ++q) dst[q] = src[q];
    }
}

// ---------------- B packing (fragment-major, both layers) ----------------
// frag id f = (s*8 + q2)*64 + ln  (q2 = tn*2+h), 16B each:
//   col = tn*16 + (ln&15), koff = h*32 + (ln>>4)*8 + j, j=0..7
//   s<64:  nn_w[koff*4096 + s*64 + col] ; s==64: nn_b[koff*64 + col]
__global__ void pack_b_kernel(const float* __restrict__ nw0, const float* __restrict__ nb0,
                              const float* __restrict__ nw1, const float* __restrict__ nb1,
                              f16* __restrict__ Bp0, f16* __restrict__ Bp1) {
    int idx = blockIdx.x * 256 + threadIdx.x;
    if (idx >= 2 * NSTAGES * 2048) return;
    int layer = (idx >= NSTAGES * 2048) ? 1 : 0;
    int r = idx - layer * NSTAGES * 2048;
    const float* nn_w = layer ? nw1 : nw0;
    const float* nn_b = layer ? nb1 : nb0;
    f16* Bp = layer ? Bp1 : Bp0;
    int p  = r & 3;
    int f  = r >> 2;
    int ln = f & 63;
    int q2 = (f >> 6) & 7;
    int s  = f >> 9;
    int tn = q2 >> 1, h = q2 & 1;
    int col  = tn * 16 + (ln & 15);
    int koff = h * 32 + (ln >> 4) * 8 + p * 2;
    float v0, v1;
    if (s < 64) {
        v0 = nn_w[(size_t)koff * 4096 + s * 64 + col];
        v1 = nn_w[(size_t)(koff + 1) * 4096 + s * 64 + col];
    } else {
        v0 = nn_b[koff * 64 + col];
        v1 = nn_b[(koff + 1) * 64 + col];
    }
    union { f16 h2[2]; unsigned u; } pk;
    pk.h2[0] = (f16)v0; pk.h2[1] = (f16)v1;
    *(unsigned*)((char*)Bp + (size_t)f * 16 + p * 4) = pk.u;
}

// ------- edge GEMM: 1 wave, 64 sorted edges x 32 cols (by = col half) -------
// (R12 structure, measured 44.5 us; + T5 setprio around MFMA cluster)
template<bool RELU_IN>
__global__ __launch_bounds__(64, 2)
void edge_gemm_kernel(const float* __restrict__ x,
                      const int* __restrict__ esrc,   // sorted src ids
                      const float* __restrict__ eas,  // sorted ea rows
                      const f16* __restrict__ Bp,     // fragment-major
                      float* __restrict__ msg) {      // [E][64] at sorted pos
    __shared__ f16 xjS[MW][72];

    int ln  = threadIdx.x;
    int l15 = ln & 15, l4 = ln >> 4;
    int e0  = blockIdx.x * MW;
    int nh  = blockIdx.y;          // col half 0/1

    // Gather x[src] rows (fused ReLU) into LDS as f16: 64 edges x 16 float4.
#pragma unroll
    for (int r = 0; r < 16; ++r) {
        int idx = r * 64 + ln;
        int el = idx >> 4, ip = idx & 15;
        int p  = e0 + el;
        float4 v = {0.f, 0.f, 0.f, 0.f};
        if (p < NEDGES)
            v = *(const float4*)(x + (size_t)esrc[p] * CH + ip * 4);
        if (RELU_IN) {
            v.x = fmaxf(v.x, 0.f); v.y = fmaxf(v.y, 0.f);
            v.z = fmaxf(v.z, 0.f); v.w = fmaxf(v.w, 0.f);
        }
        union { f16 h4[4]; uint2 u; } pk;
        pk.h4[0] = (f16)v.x; pk.h4[1] = (f16)v.y;
        pk.h4[2] = (f16)v.z; pk.h4[3] = (f16)v.w;
        *(uint2*)&xjS[el][ip * 4] = pk.u;
    }

    // ea fragments (stage-invariant): 4 m-tiles x 2 halves, contiguous rows
    f16x8 eav[4][2];
#pragma unroll
    for (int ms = 0; ms < 4; ++ms) {
        int p = e0 + ms * 16 + l15;
#pragma unroll
        for (int h = 0; h < 2; ++h) {
            float4 a = {0.f,0.f,0.f,0.f}, b = {0.f,0.f,0.f,0.f};
            if (p < NEDGES) {
                const float4* q = (const float4*)(eas + (size_t)p * CH + h * 32 + l4 * 8);
                a = q[0]; b = q[1];
            }
            f16x8 f;
            f[0]=(f16)a.x; f[1]=(f16)a.y; f[2]=(f16)a.z; f[3]=(f16)a.w;
            f[4]=(f16)b.x; f[5]=(f16)b.y; f[6]=(f16)b.z; f[7]=(f16)b.w;
            eav[ms][h] = f;
        }
    }

    f32x4 acc[4][2];
#pragma unroll
    for (int ms = 0; ms < 4; ++ms)
#pragma unroll
        for (int tl = 0; tl < 2; ++tl)
            acc[ms][tl] = (f32x4){0.f, 0.f, 0.f, 0.f};

    const char* gB = (const char*)Bp + nh * 4096 + ln * 16;

#define LOADB(b, sidx) do {                                                     \
        const char* _p = gB + (size_t)(sidx) * 8192;                            \
        b[0] = *(const f16x8*)(_p);                                             \
        b[1] = *(const f16x8*)(_p + 1024);                                      \
        b[2] = *(const f16x8*)(_p + 2048);                                      \
        b[3] = *(const f16x8*)(_p + 3072);                                      \
    } while (0)

#define COMP(sidx, b) do {                                                      \
        __builtin_amdgcn_s_setprio(1);                                          \
        _Pragma("unroll")                                                       \
        for (int ms = 0; ms < 4; ++ms) {                                        \
            f16 xv = xjS[ms * 16 + l15][(sidx)];                                \
            f16x8 xsp = {xv, xv, xv, xv, xv, xv, xv, xv};                       \
            f16x8 a0 = eav[ms][0] * xsp;                                        \
            f16x8 a1 = eav[ms][1] * xsp;                                        \
            _Pragma("unroll")                                                   \
            for (int tl = 0; tl < 2; ++tl) {                                    \
                acc[ms][tl] = __builtin_amdgcn_mfma_f32_16x16x32_f16(a0, b[tl*2+0], acc[ms][tl], 0, 0, 0); \
                acc[ms][tl] = __builtin_amdgcn_mfma_f32_16x16x32_f16(a1, b[tl*2+1], acc[ms][tl], 0, 0, 0); \
            }                                                                   \
        }                                                                       \
        __builtin_amdgcn_s_setprio(0);                                          \
    } while (0)

#define WAIT8 do { asm volatile("s_waitcnt vmcnt(8)" ::: "memory");             \
                   __builtin_amdgcn_sched_barrier(0); } while (0)

    f16x8 b0[4], b1[4], b2[4];
    LOADB(b0, 0); LOADB(b1, 1); LOADB(b2, 2);
    asm volatile("s_waitcnt vmcnt(0)" ::: "memory");   // drain gathers + prologue
    __builtin_amdgcn_sched_barrier(0);

#pragma unroll 1
    for (int s = 0; s < 63; s += 3) {
        WAIT8; COMP(s,     b0); LOADB(b0, s + 3);
        WAIT8; COMP(s + 1, b1); LOADB(b1, s + 4);
        WAIT8; COMP(s + 2, b2); LOADB(b2, min(s + 5, 64));
    }
    // outstanding: b0(63), b1(64), b2(64dup) = 12 loads
    WAIT8;                                              // b0(63) landed
    COMP(63, b0);
    asm volatile("s_waitcnt vmcnt(4)" ::: "memory");    // b1(64) landed
    __builtin_amdgcn_sched_barrier(0);
    // bias stage: A[e][i] = xj[e][i], B = b1 (stage 64)
    __builtin_amdgcn_s_setprio(1);
#pragma unroll
    for (int ms = 0; ms < 4; ++ms)
#pragma unroll
        for (int h = 0; h < 2; ++h) {
            f16x8 af = *(const f16x8*)&xjS[ms * 16 + l15][h * 32 + l4 * 8];
#pragma unroll
            for (int tl = 0; tl < 2; ++tl)
                acc[ms][tl] = __builtin_amdgcn_mfma_f32_16x16x32_f16(af, b1[tl * 2 + h], acc[ms][tl], 0, 0, 0);
        }
    __builtin_amdgcn_s_setprio(0);

    // Plain coalesced stores at sorted position, col block nh*32.
#pragma unroll
    for (int ms = 0; ms < 4; ++ms)
#pragma unroll
        for (int q = 0; q < 4; ++q) {
            int p = e0 + ms * 16 + l4 * 4 + q;
            if (p < NEDGES) {
                float* row = msg + (size_t)p * CH + nh * 32;
                row[l15]      = acc[ms][0][q];
                row[16 + l15] = acc[ms][1][q];
            }
        }
#undef LOADB
#undef COMP
#undef WAIT8
}

// ---- fused root + bias + contiguous segment reduce (+ optional final) ----
template<bool RELU_IN, bool FINAL>
__global__ __launch_bounds__(256)
void rootreduce_kernel(const float* __restrict__ x,
                       const float* __restrict__ lw,
                       const float* __restrict__ bias,
                       const float* __restrict__ msg,
                       const int* __restrict__ start,
                       const float* __restrict__ fw,
                       const float* __restrict__ fb,
                       float* __restrict__ outb) {
    __shared__ float vrow[4][64];
    int o  = threadIdx.x & 63;
    int wv = threadIdx.x >> 6;
    int gw = (blockIdx.x * 256 + threadIdx.x) >> 6;
    float lwc[64];
#pragma unroll
    for (int k = 0; k < 64; ++k) lwc[k] = lw[k * 64 + o];
    float fwc[64];
    float fbo = 0.f;
    if (FINAL) {
#pragma unroll
        for (int k = 0; k < 64; ++k) fwc[k] = fw[k * 64 + o];
        fbo = fb[o];
    }
    float bo = bias[o];
    for (int n = gw; n < NNODES; n += 1024) {
        const float4* xr = (const float4*)(x + (size_t)n * 64);
        float acc = bo;
#pragma unroll
        for (int kq = 0; kq < 16; ++kq) {
            float4 xv = xr[kq];
            float a = xv.x, b = xv.y, c = xv.z, d = xv.w;
            if (RELU_IN) {
                a = fmaxf(a, 0.f); b = fmaxf(b, 0.f);
                c = fmaxf(c, 0.f); d = fmaxf(d, 0.f);
            }
            acc = fmaf(a, lwc[kq * 4 + 0], acc);
            acc = fmaf(b, lwc[kq * 4 + 1], acc);
            acc = fmaf(c, lwc[kq * 4 + 2], acc);
            acc = fmaf(d, lwc[kq * 4 + 3], acc);
        }
        int pb = start[n], pe = start[n + 1];
        int p = pb;
        for (; p + 4 <= pe; p += 4) {
            float v0 = msg[(size_t)(p + 0) * 64 + o];
            float v1 = msg[(size_t)(p + 1) * 64 + o];
            float v2 = msg[(size_t)(p + 2) * 64 + o];
            float v3 = msg[(size_t)(p + 3) * 64 + o];
            acc += (v0 + v1) + (v2 + v3);
        }
        for (; p < pe; ++p)
            acc += msg[(size_t)p * 64 + o];
        if (FINAL) {
            vrow[wv][o] = fmaxf(acc, 0.f);
            float a2 = fbo;
#pragma unroll
            for (int k = 0; k < 64; ++k)
                a2 = fmaf(vrow[wv][k], fwc[k], a2);
            outb[(size_t)n * 64 + o] = a2;
        } else {
            outb[(size_t)n * 64 + o] = acc;
        }
    }
}

extern "C" void kernel_launch(void* const* d_in, const int* in_sizes, int n_in,
                              void* d_out, int out_size, void* d_ws, size_t ws_size,
                              hipStream_t stream) {
    const float* feature = (const float*)d_in[0];
    const int*   ei      = (const int*)d_in[1];
    const float* ea      = (const float*)d_in[2];
    const float* nn_w0   = (const float*)d_in[3];
    const float* nn_b0   = (const float*)d_in[4];
    const float* lin_w0  = (const float*)d_in[5];
    const float* bias0   = (const float*)d_in[6];
    const float* nn_w1   = (const float*)d_in[7];
    const float* nn_b1   = (const float*)d_in[8];
    const float* lin_w1  = (const float*)d_in[9];
    const float* bias1   = (const float*)d_in[10];
    const float* fin_w   = (const float*)d_in[11];
    const float* fin_b   = (const float*)d_in[12];
    float* out = (float*)d_out;

    char* ws = (char*)d_ws;
    float* buf0   = (float*)(ws + 0);                 //  2,560,000
    f16*   Bp0    = (f16*)  (ws + 2560000);           //    532,480
    f16*   Bp1    = (f16*)  (ws + 3092480);           //    532,480
    int*   hist   = (int*)  (ws + 3624960);           //     40,000
    int*   cursor = (int*)  (ws + 3664960);           //     40,000
    int*   startp = (int*)  (ws + 3704960);           //     40,016
    int*   esrc   = (int*)  (ws + 3744976);           //    200,000
    float* eas    = (float*)(ws + 3944976);           // 12,800,000
    float* msg    = (float*)(ws + 16744976);          // 12,800,000 (end ~29.5MB)

    // dst-sorted CSR + sorted ea rows (merged into perm)
    zero_kernel<<<(NNODES + 255) / 256, 256, 0, stream>>>(hist, cursor);
    hist_kernel<<<(NEDGES + 255) / 256, 256, 0, stream>>>(ei, hist);
    scan_kernel<<<1, 1024, 0, stream>>>(hist, startp);
    perm_kernel<<<(NEDGES + 255) / 256, 256, 0, stream>>>(ei, startp, cursor,
                                                          esrc, ea, eas);

    // pack both layers' B
    pack_b_kernel<<<(2 * NSTAGES * 2048 + 255) / 256, 256, 0, stream>>>(
        nn_w0, nn_b0, nn_w1, nn_b1, Bp0, Bp1);

    dim3 eg((NEDGES + MW - 1) / MW, 2);   // 782 x 2 one-wave blocks

    // layer 0
    edge_gemm_kernel<false><<<eg, 64, 0, stream>>>(feature, esrc, eas, Bp0, msg);
    rootreduce_kernel<false, false><<<256, 256, 0, stream>>>(
        feature, lin_w0, bias0, msg, startp, fin_w, fin_b, buf0);
    // layer 1 (ReLU fused into loads) + final linear fused
    edge_gemm_kernel<true><<<eg, 64, 0, stream>>>(buf0, esrc, eas, Bp1, msg);
    rootreduce_kernel<true, true><<<256, 256, 0, stream>>>(
        buf0, lin_w1, bias1, msg, startp, fin_w, fin_b, out);
}